// Round 3
// baseline (212.639 us; speedup 1.0000x reference)
//
#include <hip/hip_runtime.h>
#include <math.h>

// RWKV WKV forward, chunked parallel scan v3.
// B=8, T=2048, H=768. Depth-4 register software pipeline in phases 1/3.
// ws (SoA): wa[B][NC][H], wb[B][NC][H], we[B][NC][H] floats.

#define B_   8
#define T_   2048
#define H_   768
#define HV4_ (H_ / 4)
#define TPB_ 192   // H_/4 threads; each thread owns 4 consecutive h channels

__device__ __forceinline__ float rcp_f(float x) { return __builtin_amdgcn_rcpf(x); }

// ---------------- Phase 1: per-chunk local aggregates ----------------
template <int NC>
__global__ __launch_bounds__(TPB_) void wkv_phase1(
    const float* __restrict__ key, const float* __restrict__ val,
    const float* __restrict__ time_decay,
    float* __restrict__ wa, float* __restrict__ wb, float* __restrict__ we)
{
    constexpr int L = T_ / NC;
    constexpr int D = 4;                 // pipeline depth
    const int h0 = threadIdx.x * 4;
    const int c = blockIdx.x, b = blockIdx.y;

    const float4 td = *(const float4*)(time_decay + h0);
    const float w[4] = { -__expf(td.x), -__expf(td.y), -__expf(td.z), -__expf(td.w) };

    const size_t base = ((size_t)b * T_ + (size_t)c * L) * HV4_ + threadIdx.x;
    const float4* kp = (const float4*)key + base;
    const float4* vp = (const float4*)val + base;

    float4 kbuf[D], vbuf[D];
#pragma unroll
    for (int i = 0; i < D; ++i) {
        kbuf[i] = kp[(size_t)i * HV4_];
        vbuf[i] = vp[(size_t)i * HV4_];
    }

    float a[4] = {0.f, 0.f, 0.f, 0.f};
    float bb[4] = {0.f, 0.f, 0.f, 0.f};
    float e[4] = {-INFINITY, -INFINITY, -INFINITY, -INFINITY};

#pragma unroll
    for (int t = 0; t < L; ++t) {
        const float4 kt = kbuf[t & (D - 1)];
        const float4 vt = vbuf[t & (D - 1)];
        if (t + D < L) {
            kbuf[t & (D - 1)] = kp[(size_t)(t + D) * HV4_];
            vbuf[t & (D - 1)] = vp[(size_t)(t + D) * HV4_];
        }
        const float kk[4] = {kt.x, kt.y, kt.z, kt.w};
        const float vv[4] = {vt.x, vt.y, vt.z, vt.w};
#pragma unroll
        for (int j = 0; j < 4; ++j) {
            const float ew = e[j] + w[j];
            const float m2 = fmaxf(ew, kk[j]);
            const float s1 = __expf(ew - m2);
            const float s2 = __expf(kk[j] - m2);
            a[j]  = fmaf(s1, a[j],  s2 * vv[j]);
            bb[j] = fmaf(s1, bb[j], s2);
            e[j]  = m2;
        }
    }

    const size_t off = (((size_t)b * NC + c) * H_ + h0) >> 2;
    ((float4*)wa)[off] = make_float4(a[0], a[1], a[2], a[3]);
    ((float4*)wb)[off] = make_float4(bb[0], bb[1], bb[2], bb[3]);
    ((float4*)we)[off] = make_float4(e[0], e[1], e[2], e[3]);
}

// ---------------- Phase 2: sequential combine across chunks ----------------
// One thread per (b,h). Depth-P scalar prefetch ring over the chunk axis.
template <int NC, int P>
__global__ __launch_bounds__(256) void wkv_phase2(
    float* __restrict__ wa, float* __restrict__ wb, float* __restrict__ we,
    const float* __restrict__ time_decay)
{
    constexpr int L = T_ / NC;
    const int idx = blockIdx.x * 256 + threadIdx.x;  // 0 .. B_*H_-1
    const int b = idx / H_;
    const int h = idx - b * H_;

    const float wL = -__expf(time_decay[h]) * (float)L;

    const size_t off0 = (size_t)b * NC * H_ + h;
    float ca[P], cb[P], ce[P];
#pragma unroll
    for (int p = 0; p < P; ++p) {
        ca[p] = wa[off0 + (size_t)p * H_];
        cb[p] = wb[off0 + (size_t)p * H_];
        ce[p] = we[off0 + (size_t)p * H_];
    }

    float ra = 0.f, rb = 0.f, re = -INFINITY;
#pragma unroll 16
    for (int c = 0; c < NC; ++c) {
        const int s = c & (P - 1);
        const float xa = ca[s], xb = cb[s], xe = ce[s];
        if (c + P < NC) {
            const size_t noff = off0 + (size_t)(c + P) * H_;
            ca[s] = wa[noff]; cb[s] = wb[noff]; ce[s] = we[noff];
        }
        const size_t coff = off0 + (size_t)c * H_;
        wa[coff] = ra; wb[coff] = rb; we[coff] = re;   // incoming state for chunk c

        const float e1 = re + wL;
        const float m  = fmaxf(e1, xe);
        const float p_ = __expf(e1 - m);
        const float q_ = __expf(xe - m);
        ra = fmaf(ra, p_, xa * q_);
        rb = fmaf(rb, p_, xb * q_);
        re = m;
    }
}

// ---------------- Phase 3: replay each chunk, emit wkv ----------------
template <int NC>
__global__ __launch_bounds__(TPB_) void wkv_phase3(
    const float* __restrict__ key, const float* __restrict__ val,
    const float* __restrict__ time_decay, const float* __restrict__ time_first,
    const float* __restrict__ wa, const float* __restrict__ wb,
    const float* __restrict__ we, float* __restrict__ out)
{
    constexpr int L = T_ / NC;
    constexpr int D = 4;
    const int h0 = threadIdx.x * 4;
    const int c = blockIdx.x, b = blockIdx.y;

    const float4 td = *(const float4*)(time_decay + h0);
    const float4 tf = *(const float4*)(time_first + h0);
    const float w[4] = { -__expf(td.x), -__expf(td.y), -__expf(td.z), -__expf(td.w) };
    const float u[4] = { tf.x, tf.y, tf.z, tf.w };

    const size_t soff = (((size_t)b * NC + c) * H_ + h0) >> 2;
    const float4 sa = ((const float4*)wa)[soff];
    const float4 sb = ((const float4*)wb)[soff];
    const float4 se = ((const float4*)we)[soff];
    float a[4]  = {sa.x, sa.y, sa.z, sa.w};
    float bb[4] = {sb.x, sb.y, sb.z, sb.w};
    float e[4]  = {se.x, se.y, se.z, se.w};

    const size_t base = ((size_t)b * T_ + (size_t)c * L) * HV4_ + threadIdx.x;
    const float4* kp = (const float4*)key + base;
    const float4* vp = (const float4*)val + base;
    float4*       op = (float4*)out + base;

    float4 kbuf[D], vbuf[D];
#pragma unroll
    for (int i = 0; i < D; ++i) {
        kbuf[i] = kp[(size_t)i * HV4_];
        vbuf[i] = vp[(size_t)i * HV4_];
    }

#pragma unroll
    for (int t = 0; t < L; ++t) {
        const float4 kt = kbuf[t & (D - 1)];
        const float4 vt = vbuf[t & (D - 1)];
        if (t + D < L) {
            kbuf[t & (D - 1)] = kp[(size_t)(t + D) * HV4_];
            vbuf[t & (D - 1)] = vp[(size_t)(t + D) * HV4_];
        }
        const float kk[4] = {kt.x, kt.y, kt.z, kt.w};
        const float vv[4] = {vt.x, vt.y, vt.z, vt.w};
        float o[4];
#pragma unroll
        for (int j = 0; j < 4; ++j) {
            // wkv output (state BEFORE update)
            const float uk = u[j] + kk[j];
            const float m1 = fmaxf(e[j], uk);
            const float wt = __expf(uk - m1);
            const float sc = __expf(e[j] - m1);
            const float num = fmaf(a[j],  sc, wt * vv[j]);
            const float den = fmaf(bb[j], sc, wt);
            o[j] = num * rcp_f(den);

            // state update
            const float ew = e[j] + w[j];
            const float m2 = fmaxf(ew, kk[j]);
            const float s1 = __expf(ew - m2);
            const float s2 = __expf(kk[j] - m2);
            a[j]  = fmaf(s1, a[j],  s2 * vv[j]);
            bb[j] = fmaf(s1, bb[j], s2);
            e[j]  = m2;
        }
        op[(size_t)t * HV4_] = make_float4(o[0], o[1], o[2], o[3]);
    }
}

// ---------------- launcher ----------------
template <int NC>
static void launch_all(const float* key, const float* val, const float* td,
                       const float* tf, float* out, float* ws, hipStream_t stream)
{
    float* wa = ws;
    float* wb = wa + (size_t)B_ * NC * H_;
    float* we = wb + (size_t)B_ * NC * H_;

    dim3 grid13(NC, B_);
    wkv_phase1<NC><<<grid13, dim3(TPB_), 0, stream>>>(key, val, td, wa, wb, we);

    dim3 grid2((B_ * H_) / 256);
    wkv_phase2<NC, 16><<<grid2, dim3(256), 0, stream>>>(wa, wb, we, td);

    wkv_phase3<NC><<<grid13, dim3(TPB_), 0, stream>>>(key, val, td, tf, wa, wb, we, out);
}

extern "C" void kernel_launch(void* const* d_in, const int* in_sizes, int n_in,
                              void* d_out, int out_size, void* d_ws, size_t ws_size,
                              hipStream_t stream) {
    const float* key = (const float*)d_in[0];
    const float* val = (const float*)d_in[1];
    const float* td  = (const float*)d_in[2];
    const float* tf  = (const float*)d_in[3];
    float* out = (float*)d_out;
    float* ws = (float*)d_ws;

    const size_t needNC = (size_t)3 * B_ * H_ * sizeof(float);  // per chunk
    if (ws_size >= 128 * needNC)      launch_all<128>(key, val, td, tf, out, ws, stream);
    else if (ws_size >= 64 * needNC)  launch_all<64>(key, val, td, tf, out, ws, stream);
    else if (ws_size >= 32 * needNC)  launch_all<32>(key, val, td, tf, out, ws, stream);
    else                              launch_all<16>(key, val, td, tf, out, ws, stream);
}

// Round 4
// 169.030 us; speedup vs baseline: 1.2580x; 1.2580x over previous
//
#include <hip/hip_runtime.h>
#include <math.h>

// RWKV WKV forward, chunked parallel scan v4.
// B=8, T=2048, H=768. Scalar one-h-per-thread phases 1/3 for max occupancy.
// ws layout (6 disjoint arrays of B*NC*H floats):
//   aggA aggB aggE  (phase1 out -> phase2 in)
//   stA  stB  stE   (phase2 out -> phase3 in)   [no aliasing!]

#define B_   8
#define T_   2048
#define H_   768

__device__ __forceinline__ float rcp_f(float x) { return __builtin_amdgcn_rcpf(x); }

// ---------------- Phase 1: per-chunk local aggregates ----------------
// grid (H/256, NC, B), block 256; thread = one (b, c, h).
template <int NC>
__global__ __launch_bounds__(256) void wkv_phase1(
    const float* __restrict__ key, const float* __restrict__ val,
    const float* __restrict__ time_decay,
    float* __restrict__ aggA, float* __restrict__ aggB, float* __restrict__ aggE)
{
    constexpr int L = T_ / NC;
    constexpr int D = 4;
    const int h = blockIdx.x * 256 + threadIdx.x;
    const int c = blockIdx.y, b = blockIdx.z;

    const float w = -__expf(time_decay[h]);

    const size_t base = ((size_t)b * T_ + (size_t)c * L) * H_ + h;
    const float* kp = key + base;
    const float* vp = val + base;

    float kbuf[D], vbuf[D];
#pragma unroll
    for (int i = 0; i < D; ++i) {
        kbuf[i] = kp[(size_t)i * H_];
        vbuf[i] = vp[(size_t)i * H_];
    }

    float a = 0.f, bb = 0.f, e = -INFINITY;
#pragma unroll
    for (int t = 0; t < L; ++t) {
        const float kt = kbuf[t & (D - 1)];
        const float vt = vbuf[t & (D - 1)];
        if (t + D < L) {
            kbuf[t & (D - 1)] = kp[(size_t)(t + D) * H_];
            vbuf[t & (D - 1)] = vp[(size_t)(t + D) * H_];
        }
        const float ew = e + w;
        const float m2 = fmaxf(ew, kt);
        const float s1 = __expf(ew - m2);
        const float s2 = __expf(kt - m2);
        a  = fmaf(s1, a,  s2 * vt);
        bb = fmaf(s1, bb, s2);
        e  = m2;
    }

    const size_t off = ((size_t)b * NC + c) * H_ + h;
    aggA[off] = a; aggB[off] = bb; aggE[off] = e;
}

// ---------------- Phase 2: sequential combine across chunks ----------------
// One thread per (b,h). Reads agg* (const), writes st* (disjoint) -> no alias
// stalls. P-deep register prefetch ring.
template <int NC, int P>
__global__ __launch_bounds__(256) void wkv_phase2(
    const float* __restrict__ aggA, const float* __restrict__ aggB,
    const float* __restrict__ aggE,
    float* __restrict__ stA, float* __restrict__ stB, float* __restrict__ stE,
    const float* __restrict__ time_decay)
{
    constexpr int L = T_ / NC;
    const int idx = blockIdx.x * 256 + threadIdx.x;  // 0 .. B_*H_-1
    const int b = idx / H_;
    const int h = idx - b * H_;

    const float wL = -__expf(time_decay[h]) * (float)L;

    const size_t off0 = (size_t)b * NC * H_ + h;
    float ca[P], cb[P], ce[P];
#pragma unroll
    for (int p = 0; p < P; ++p) {
        const size_t o = off0 + (size_t)p * H_;
        ca[p] = aggA[o]; cb[p] = aggB[o]; ce[p] = aggE[o];
    }

    float ra = 0.f, rb = 0.f, re = -INFINITY;
#pragma unroll
    for (int c = 0; c < NC; ++c) {
        const int s = c & (P - 1);
        const float xa = ca[s], xb = cb[s], xe = ce[s];
        if (c + P < NC) {
            const size_t noff = off0 + (size_t)(c + P) * H_;
            ca[s] = aggA[noff]; cb[s] = aggB[noff]; ce[s] = aggE[noff];
        }
        const size_t coff = off0 + (size_t)c * H_;
        stA[coff] = ra; stB[coff] = rb; stE[coff] = re;  // incoming state for chunk c

        const float e1 = re + wL;
        const float m  = fmaxf(e1, xe);
        const float p_ = __expf(e1 - m);
        const float q_ = __expf(xe - m);
        ra = fmaf(ra, p_, xa * q_);
        rb = fmaf(rb, p_, xb * q_);
        re = m;
    }
}

// ---------------- Phase 3: replay each chunk, emit wkv ----------------
template <int NC>
__global__ __launch_bounds__(256) void wkv_phase3(
    const float* __restrict__ key, const float* __restrict__ val,
    const float* __restrict__ time_decay, const float* __restrict__ time_first,
    const float* __restrict__ stA, const float* __restrict__ stB,
    const float* __restrict__ stE, float* __restrict__ out)
{
    constexpr int L = T_ / NC;
    constexpr int D = 4;
    const int h = blockIdx.x * 256 + threadIdx.x;
    const int c = blockIdx.y, b = blockIdx.z;

    const float u = time_first[h];
    const float w = -__expf(time_decay[h]);

    const size_t soff = ((size_t)b * NC + c) * H_ + h;
    float a  = stA[soff];
    float bb = stB[soff];
    float e  = stE[soff];

    const size_t base = ((size_t)b * T_ + (size_t)c * L) * H_ + h;
    const float* kp = key + base;
    const float* vp = val + base;
    float*       op = out + base;

    float kbuf[D], vbuf[D];
#pragma unroll
    for (int i = 0; i < D; ++i) {
        kbuf[i] = kp[(size_t)i * H_];
        vbuf[i] = vp[(size_t)i * H_];
    }

#pragma unroll
    for (int t = 0; t < L; ++t) {
        const float kt = kbuf[t & (D - 1)];
        const float vt = vbuf[t & (D - 1)];
        if (t + D < L) {
            kbuf[t & (D - 1)] = kp[(size_t)(t + D) * H_];
            vbuf[t & (D - 1)] = vp[(size_t)(t + D) * H_];
        }

        // wkv output (state BEFORE update)
        const float uk = u + kt;
        const float m1 = fmaxf(e, uk);
        const float wt = __expf(uk - m1);
        const float sc = __expf(e - m1);
        const float num = fmaf(a,  sc, wt * vt);
        const float den = fmaf(bb, sc, wt);
        op[(size_t)t * H_] = num * rcp_f(den);

        // state update
        const float ew = e + w;
        const float m2 = fmaxf(ew, kt);
        const float s1 = __expf(ew - m2);
        const float s2 = __expf(kt - m2);
        a  = fmaf(s1, a,  s2 * vt);
        bb = fmaf(s1, bb, s2);
        e  = m2;
    }
}

// ---------------- launcher ----------------
template <int NC>
static void launch_all(const float* key, const float* val, const float* td,
                       const float* tf, float* out, float* ws, hipStream_t stream)
{
    const size_t n = (size_t)B_ * NC * H_;
    float* aggA = ws;
    float* aggB = aggA + n;
    float* aggE = aggB + n;
    float* stA  = aggE + n;
    float* stB  = stA + n;
    float* stE  = stB + n;

    dim3 grid13(H_ / 256, NC, B_);
    wkv_phase1<NC><<<grid13, dim3(256), 0, stream>>>(key, val, td, aggA, aggB, aggE);

    dim3 grid2((B_ * H_) / 256);
    wkv_phase2<NC, 8><<<grid2, dim3(256), 0, stream>>>(aggA, aggB, aggE, stA, stB, stE, td);

    wkv_phase3<NC><<<grid13, dim3(256), 0, stream>>>(key, val, td, tf, stA, stB, stE, out);
}

extern "C" void kernel_launch(void* const* d_in, const int* in_sizes, int n_in,
                              void* d_out, int out_size, void* d_ws, size_t ws_size,
                              hipStream_t stream) {
    const float* key = (const float*)d_in[0];
    const float* val = (const float*)d_in[1];
    const float* td  = (const float*)d_in[2];
    const float* tf  = (const float*)d_in[3];
    float* out = (float*)d_out;
    float* ws = (float*)d_ws;

    const size_t perNC = (size_t)6 * B_ * H_ * sizeof(float);  // 6 arrays per chunk
    if (ws_size >= 128 * perNC)      launch_all<128>(key, val, td, tf, out, ws, stream);
    else if (ws_size >= 64 * perNC)  launch_all<64>(key, val, td, tf, out, ws, stream);
    else if (ws_size >= 32 * perNC)  launch_all<32>(key, val, td, tf, out, ws, stream);
    else                             launch_all<16>(key, val, td, tf, out, ws, stream);
}